// Round 7
// baseline (536.951 us; speedup 1.0000x reference)
//
#include <hip/hip_runtime.h>
#include <stdint.h>

#define SEQ 1024
#define NB  1024
#define HD  64
#define BH  (NB*HD)            // elements per timestep plane
#define RPB 16                 // batch rows per block

typedef _Float16 f16x8 __attribute__((ext_vector_type(8)));
typedef float    f32x4 __attribute__((ext_vector_type(4)));
typedef uint32_t u32x4 __attribute__((ext_vector_type(4)));

#define L2E2 2.8853900817779268f   // 2*log2(e), folded into weights/bias

__device__ __forceinline__ uint32_t pkrtz(float a, float b) {
    auto h = __builtin_amdgcn_cvt_pkrtz(a, b);   // a->lo, b->hi
    return __builtin_bit_cast(uint32_t, h);
}
// tanh from prescaled z = 2*log2e*x: tanh(x) = sign(z)*(2/(1+exp2(-|z|)) - 1)
__device__ __forceinline__ float tanh_ps(float z) {
    float e = __builtin_amdgcn_exp2f(-__builtin_fabsf(z));
    float r = __builtin_amdgcn_rcpf(e + 1.0f);
    float m = __builtin_fmaf(2.0f, r, -1.0f);
    return __builtin_copysignf(m, z);
}
// Barrier draining ONLY lgkmcnt: global loads/stores stay in flight.
__device__ __forceinline__ void sync_lds() {
    asm volatile("s_waitcnt lgkmcnt(0)" ::: "memory");
    __builtin_amdgcn_s_barrier();
    asm volatile("" ::: "memory");
}

__global__ __launch_bounds__(512, 1) void rnn_kernel(
    const float* __restrict__ x,  const float* __restrict__ h0,
    const float* __restrict__ Wx, const float* __restrict__ bx,
    const float* __restrict__ Wh, const float* __restrict__ bh,
    float* __restrict__ out)
{
    // h frag dwords: [buf][T][chan-quad q][lane]  (conflict-free both sides)
    __shared__ uint32_t hw[2][2][4][64];       // 4 KB
    // xp C-fragments: [buf][tile p][lane] as f32x4 (b128 both sides)
    __shared__ __align__(16) f32x4 xpl[2][4][64];  // 8 KB

    const int tid  = threadIdx.x;
    const int w    = tid >> 6;         // wave 0..7
    const int lane = tid & 63;
    const int g    = lane >> 4;        // 16-lane group
    const int n    = lane & 15;        // MFMA col = batch row (all 16 valid)
    const int R0   = blockIdx.x * RPB;
    const size_t row = (size_t)(R0 + n) * HD;

    if (w < 4) {
        // ================= CONSUMER: recurrence only =================
        // K-permuted prescaled Wh A-frags for channels [16w,16w+16):
        // frag[T] elem e (k=8g+e) = Wh[16w+n][16(e>>1)+4g+2T+(e&1)] * L2E2
        f16x8 whA[2];
        #pragma unroll
        for (int T = 0; T < 2; ++T) {
            u32x4 dw;
            #pragma unroll
            for (int q = 0; q < 4; ++q) {
                const int c = 16*q + 4*g + 2*T;
                const float* wp = Wh + (size_t)(16*w + n) * HD + c;
                dw[q] = pkrtz(wp[0]*L2E2, wp[1]*L2E2);
            }
            whA[T] = __builtin_bit_cast(f16x8, dw);
        }
        // stage h(0) pairs for own channel quad
        {
            f32x4 hv = *(const f32x4*)(h0 + row + 16*w + 4*g);
            hw[0][0][w][lane] = pkrtz(hv[0], hv[1]);
            hw[0][1][w][lane] = pkrtz(hv[2], hv[3]);
        }
        sync_lds();
        __builtin_amdgcn_s_setprio(1);     // chain-critical waves win arbitration

        const f32x4 zf = {0.f, 0.f, 0.f, 0.f};
        for (int tb = 0; tb < SEQ; tb += 2) {
            #pragma unroll
            for (int u = 0; u < 2; ++u) {
                const int t = tb + u;
                const int P = u, Q = u ^ 1;

                // LDS reads first (xp b128, then fh0 quad, then fh1 quad)
                f32x4 xpC = xpl[P][w][lane];
                u32x4 hc0, hc1;
                #pragma unroll
                for (int q = 0; q < 4; ++q) hc0[q] = hw[P][0][q][lane];
                #pragma unroll
                for (int q = 0; q < 4; ++q) hc1[q] = hw[P][1][q][lane];
                f16x8 fh0 = __builtin_bit_cast(f16x8, hc0);
                f16x8 fh1 = __builtin_bit_cast(f16x8, hc1);

                f32x4 pA = __builtin_amdgcn_mfma_f32_16x16x32_f16(whA[0], fh0, xpC, 0, 0, 0);
                f32x4 pB = __builtin_amdgcn_mfma_f32_16x16x32_f16(whA[1], fh1, zf,  0, 0, 0);
                f32x4 acc = pA + pB;

                f32x4 tv;
                #pragma unroll
                for (int r = 0; r < 4; ++r) tv[r] = tanh_ps(acc[r]);

                // h(t+1) pairs ARE next B-frag dwords (K-permute), 2 writes
                hw[Q][0][w][lane] = pkrtz(tv[0], tv[1]);
                hw[Q][1][w][lane] = pkrtz(tv[2], tv[3]);

                // global store, fresh address from arg (no pointer PHI)
                {
                    float* dst = out + (size_t)t * BH + row + 16*w + 4*g;
                    *(f32x4*)dst = tv;
                    if (t == SEQ - 1) {
                        float* dl = out + (size_t)SEQ * BH + row + 16*w + 4*g;
                        *(f32x4*)dl = tv;
                    }
                }
                sync_lds();
            }
        }
    } else {
        // ================= PRODUCER: xp(t) = Wx*x(t) + b =================
        const int p = w - 4;               // xp tile = channels [16p,16p+16)
        f16x8 wxA[2];
        #pragma unroll
        for (int T = 0; T < 2; ++T) {
            u32x4 dx;
            #pragma unroll
            for (int q = 0; q < 4; ++q) {
                const int c = 16*q + 4*g + 2*T;
                const float* xr = Wx + (size_t)(16*p + n) * HD + c;
                dx[q] = pkrtz(xr[0]*L2E2, xr[1]*L2E2);
            }
            wxA[T] = __builtin_bit_cast(f16x8, dx);
        }
        f32x4 biasf;
        {
            f32x4 b1 = *(const f32x4*)(bh + 16*p + 4*g);
            f32x4 b2 = *(const f32x4*)(bx + 16*p + 4*g);
            biasf = (b1 + b2) * L2E2;
        }
        // xp(0) straight from x(0)
        {
            u32x4 c0, c1;
            #pragma unroll
            for (int q = 0; q < 4; ++q) {
                f32x4 v = *(const f32x4*)(x + row + 16*q + 4*g);
                c0[q] = pkrtz(v[0], v[1]);
                c1[q] = pkrtz(v[2], v[3]);
            }
            f16x8 f0 = __builtin_bit_cast(f16x8, c0);
            f16x8 f1 = __builtin_bit_cast(f16x8, c1);
            f32x4 tq = __builtin_amdgcn_mfma_f32_16x16x32_f16(wxA[0], f0, biasf, 0, 0, 0);
            xpl[0][p][lane] = __builtin_amdgcn_mfma_f32_16x16x32_f16(wxA[1], f1, tq, 0, 0, 0);
        }
        // reg ring: slot s&3 holds x(s); preload x(1..4)
        f32x4 ring[4][4];
        #pragma unroll
        for (int s = 1; s <= 4; ++s) {
            const float* xs = x + (size_t)s * BH + row;
            #pragma unroll
            for (int q = 0; q < 4; ++q) ring[s & 3][q] = *(const f32x4*)(xs + 16*q + 4*g);
        }
        sync_lds();

        for (int tb = 0; tb < SEQ; tb += 4) {
            #pragma unroll
            for (int u = 0; u < 4; ++u) {
                const int t    = tb + u;
                const int slot = (u + 1) & 3;      // holds x(t+1), static index
                const int B    = (u + 1) & 1;      // xp dest buffer

                // pack x(t+1) into K-permuted B-frags
                u32x4 c0, c1;
                #pragma unroll
                for (int q = 0; q < 4; ++q) {
                    f32x4 v = ring[slot][q];
                    c0[q] = pkrtz(v[0], v[1]);
                    c1[q] = pkrtz(v[2], v[3]);
                }
                f16x8 f0 = __builtin_bit_cast(f16x8, c0);
                f16x8 f1 = __builtin_bit_cast(f16x8, c1);
                f32x4 tq = __builtin_amdgcn_mfma_f32_16x16x32_f16(wxA[0], f0, biasf, 0, 0, 0);
                xpl[B][p][lane] = __builtin_amdgcn_mfma_f32_16x16x32_f16(wxA[1], f1, tq, 0, 0, 0);

                // refill slot with x(t+5) (fire & forget, 4-step lead)
                {
                    int tl = t + 5; tl = tl > SEQ - 1 ? SEQ - 1 : tl;
                    const float* xs = x + (size_t)tl * BH + row;
                    #pragma unroll
                    for (int q = 0; q < 4; ++q) ring[slot][q] = *(const f32x4*)(xs + 16*q + 4*g);
                }
                sync_lds();
            }
        }
    }
}

extern "C" void kernel_launch(void* const* d_in, const int* in_sizes, int n_in,
                              void* d_out, int out_size, void* d_ws, size_t ws_size,
                              hipStream_t stream) {
    const float* x  = (const float*)d_in[0];
    const float* h  = (const float*)d_in[1];
    const float* Wx = (const float*)d_in[2];
    const float* bx = (const float*)d_in[3];
    const float* Wh = (const float*)d_in[4];
    const float* bh = (const float*)d_in[5];
    float* out = (float*)d_out;

    rnn_kernel<<<dim3(NB / RPB), dim3(512), 0, stream>>>(x, h, Wx, bx, Wh, bh, out);
}

// Round 8
// 342.693 us; speedup vs baseline: 1.5669x; 1.5669x over previous
//
#include <hip/hip_runtime.h>
#include <stdint.h>

#define SEQ 1024
#define NB  1024
#define HD  64
#define BH  (NB*HD)            // elements per timestep plane
#define RPB 16                 // batch rows per block

typedef _Float16 f16x8 __attribute__((ext_vector_type(8)));
typedef float    f32x4 __attribute__((ext_vector_type(4)));
typedef uint32_t u32x4 __attribute__((ext_vector_type(4)));

#define L2E2 2.8853900817779268f   // 2*log2(e), folded into weights/bias

__device__ __forceinline__ uint32_t pkrtz(float a, float b) {
    auto h = __builtin_amdgcn_cvt_pkrtz(a, b);   // a->lo, b->hi
    return __builtin_bit_cast(uint32_t, h);
}
// tanh from prescaled z = 2*log2e*x: tanh(x) = sign(z)*(2/(1+exp2(-|z|)) - 1)
__device__ __forceinline__ float tanh_ps(float z) {
    float e = __builtin_amdgcn_exp2f(-__builtin_fabsf(z));
    float r = __builtin_amdgcn_rcpf(e + 1.0f);
    float m = __builtin_fmaf(2.0f, r, -1.0f);
    return __builtin_copysignf(m, z);
}
// Barrier draining ONLY lgkmcnt: global loads/stores stay in flight.
__device__ __forceinline__ void sync_lds() {
    asm volatile("s_waitcnt lgkmcnt(0)" ::: "memory");
    __builtin_amdgcn_s_barrier();
    asm volatile("" ::: "memory");
}

__global__ __launch_bounds__(512, 1) void rnn_kernel(
    const float* __restrict__ x,  const float* __restrict__ h0,
    const float* __restrict__ Wx, const float* __restrict__ bx,
    const float* __restrict__ Wh, const float* __restrict__ bh,
    float* __restrict__ out)
{
    // frag dword pairs: [buf][quad q][lane][T]  -> b64 ops, ~2-way banks (free)
    __shared__ uint32_t hw[2][4][64][2];               // 4 KB
    __shared__ uint32_t xw[2][4][64][2];               // 4 KB
    // xp C-fragments: [buf][tile p][lane] f32x4      -> b128 standard pattern
    __shared__ __align__(16) f32x4 xpl[2][4][64];      // 8 KB

    const int tid  = threadIdx.x;
    const int w    = tid >> 6;         // wave 0..7
    const int lane = tid & 63;
    const int g    = lane >> 4;        // 16-lane group
    const int n    = lane & 15;        // MFMA col = batch row (all 16 valid)
    const int R0   = blockIdx.x * RPB;
    const size_t row = (size_t)(R0 + n) * HD;

    if (w < 4) {
        // ================= CONSUMER: recurrence only =================
        // K-permuted prescaled Wh A-frags for channels [16w,16w+16):
        // frag[T] elem e (k=8g+e) = Wh[16w+n][16(e>>1)+4g+2T+(e&1)] * L2E2
        f16x8 whA[2];
        #pragma unroll
        for (int T = 0; T < 2; ++T) {
            u32x4 dw;
            #pragma unroll
            for (int q = 0; q < 4; ++q) {
                const int c = 16*q + 4*g + 2*T;
                const float* wp = Wh + (size_t)(16*w + n) * HD + c;
                dw[q] = pkrtz(wp[0]*L2E2, wp[1]*L2E2);
            }
            whA[T] = __builtin_bit_cast(f16x8, dw);
        }
        // stage h(0): pairs (16w+4g+0,+1),(+2,+3) -> quad w, lane, T=0/1
        {
            f32x4 hv = *(const f32x4*)(h0 + row + 16*w + 4*g);
            *(uint2*)&hw[0][w][lane][0] = make_uint2(pkrtz(hv[0], hv[1]),
                                                     pkrtz(hv[2], hv[3]));
        }
        sync_lds();                        // #1 (match producer)
        sync_lds();                        // #2 (xpl[0] now valid)
        __builtin_amdgcn_s_setprio(1);

        const f32x4 zf = {0.f, 0.f, 0.f, 0.f};
        for (int tb = 0; tb < SEQ; tb += 2) {
            #pragma unroll
            for (int u = 0; u < 2; ++u) {
                const int t = tb + u;
                const int P = u, Q = u ^ 1;

                f32x4 xpC = xpl[P][w][lane];
                uint2 d0 = *(const uint2*)&hw[P][0][lane][0];
                uint2 d1 = *(const uint2*)&hw[P][1][lane][0];
                uint2 d2 = *(const uint2*)&hw[P][2][lane][0];
                uint2 d3 = *(const uint2*)&hw[P][3][lane][0];
                u32x4 c0, c1;
                c0[0]=d0.x; c0[1]=d1.x; c0[2]=d2.x; c0[3]=d3.x;
                c1[0]=d0.y; c1[1]=d1.y; c1[2]=d2.y; c1[3]=d3.y;
                f16x8 fh0 = __builtin_bit_cast(f16x8, c0);
                f16x8 fh1 = __builtin_bit_cast(f16x8, c1);

                f32x4 pA = __builtin_amdgcn_mfma_f32_16x16x32_f16(whA[0], fh0, xpC, 0, 0, 0);
                f32x4 pB = __builtin_amdgcn_mfma_f32_16x16x32_f16(whA[1], fh1, zf,  0, 0, 0);
                f32x4 acc = pA + pB;

                f32x4 tv;
                #pragma unroll
                for (int r = 0; r < 4; ++r) tv[r] = tanh_ps(acc[r]);

                // h(t+1) pairs ARE next-step B-frag dwords (K-permute)
                *(uint2*)&hw[Q][w][lane][0] = make_uint2(pkrtz(tv[0], tv[1]),
                                                         pkrtz(tv[2], tv[3]));
                // off-chain store (vmcnt never drained)
                {
                    float* dst = out + (size_t)t * BH + row + 16*w + 4*g;
                    *(f32x4*)dst = tv;
                    if (t == SEQ - 1)
                        *(f32x4*)(out + (size_t)SEQ * BH + row + 16*w + 4*g) = tv;
                }
                sync_lds();
            }
        }
    } else {
        // ============ PRODUCER p: x quadrant + xp tile [16p,16p+16) ============
        const int p = w - 4;
        f16x8 wxA[2];
        #pragma unroll
        for (int T = 0; T < 2; ++T) {
            u32x4 dx;
            #pragma unroll
            for (int q = 0; q < 4; ++q) {
                const int c = 16*q + 4*g + 2*T;
                const float* xr = Wx + (size_t)(16*p + n) * HD + c;
                dx[q] = pkrtz(xr[0]*L2E2, xr[1]*L2E2);
            }
            wxA[T] = __builtin_bit_cast(f16x8, dx);
        }
        f32x4 biasf;
        {
            f32x4 b1 = *(const f32x4*)(bh + 16*p + 4*g);
            f32x4 b2 = *(const f32x4*)(bx + 16*p + 4*g);
            biasf = (b1 + b2) * L2E2;
        }
        const size_t qoff = row + 16*p + 4*g;   // this lane's x slice (quad p)

        // pack+stage x(0)->xw[0], x(1)->xw[1] (own quadrant only)
        {
            f32x4 v0 = *(const f32x4*)(x + qoff);
            *(uint2*)&xw[0][p][lane][0] = make_uint2(pkrtz(v0[0], v0[1]),
                                                     pkrtz(v0[2], v0[3]));
            f32x4 v1 = *(const f32x4*)(x + (size_t)BH + qoff);
            *(uint2*)&xw[1][p][lane][0] = make_uint2(pkrtz(v1[0], v1[1]),
                                                     pkrtz(v1[2], v1[3]));
        }
        // slots (16 regs total): s0<-x(2), s1<-x(3); s2/s3 filled in loop
        f32x4 s0 = *(const f32x4*)(x + (size_t)2 * BH + qoff);
        f32x4 s1 = *(const f32x4*)(x + (size_t)3 * BH + qoff);
        f32x4 s2, s3;

        sync_lds();   // #1: xw[0], xw[1] visible

        // xp(0) from full x(0) frag
        {
            uint2 e0 = *(const uint2*)&xw[0][0][lane][0];
            uint2 e1 = *(const uint2*)&xw[0][1][lane][0];
            uint2 e2 = *(const uint2*)&xw[0][2][lane][0];
            uint2 e3 = *(const uint2*)&xw[0][3][lane][0];
            u32x4 c0, c1;
            c0[0]=e0.x; c0[1]=e1.x; c0[2]=e2.x; c0[3]=e3.x;
            c1[0]=e0.y; c1[1]=e1.y; c1[2]=e2.y; c1[3]=e3.y;
            f16x8 fx0 = __builtin_bit_cast(f16x8, c0);
            f16x8 fx1 = __builtin_bit_cast(f16x8, c1);
            const f32x4 zf = {0.f, 0.f, 0.f, 0.f};
            f32x4 tA = __builtin_amdgcn_mfma_f32_16x16x32_f16(wxA[0], fx0, biasf, 0, 0, 0);
            f32x4 tB = __builtin_amdgcn_mfma_f32_16x16x32_f16(wxA[1], fx1, zf,    0, 0, 0);
            xpl[0][p][lane] = tA + tB;
        }
        sync_lds();   // #2

        const f32x4 zf = {0.f, 0.f, 0.f, 0.f};
        for (int tb = 0; tb < SEQ; tb += 4) {
            #pragma unroll
            for (int u = 0; u < 4; ++u) {
                const int t = tb + u;
                const int RB = (u + 1) & 1;    // xw buf holding x(t+1); xp dest buf
                const int WB = u & 1;          // xw buf receiving x(t+2)

                // xp(t+1) from full x(t+1) frag (written last step)
                {
                    uint2 e0 = *(const uint2*)&xw[RB][0][lane][0];
                    uint2 e1 = *(const uint2*)&xw[RB][1][lane][0];
                    uint2 e2 = *(const uint2*)&xw[RB][2][lane][0];
                    uint2 e3 = *(const uint2*)&xw[RB][3][lane][0];
                    u32x4 c0, c1;
                    c0[0]=e0.x; c0[1]=e1.x; c0[2]=e2.x; c0[3]=e3.x;
                    c1[0]=e0.y; c1[1]=e1.y; c1[2]=e2.y; c1[3]=e3.y;
                    f16x8 fx0 = __builtin_bit_cast(f16x8, c0);
                    f16x8 fx1 = __builtin_bit_cast(f16x8, c1);
                    f32x4 tA = __builtin_amdgcn_mfma_f32_16x16x32_f16(wxA[0], fx0, biasf, 0, 0, 0);
                    f32x4 tB = __builtin_amdgcn_mfma_f32_16x16x32_f16(wxA[1], fx1, zf,    0, 0, 0);
                    xpl[RB][p][lane] = tA + tB;
                }
                // pack x(t+2) from slot u (loaded 2 steps ago; compiler vmcnt)
                {
                    f32x4 v = (u == 0) ? s0 : (u == 1) ? s1 : (u == 2) ? s2 : s3;
                    *(uint2*)&xw[WB][p][lane][0] = make_uint2(pkrtz(v[0], v[1]),
                                                              pkrtz(v[2], v[3]));
                }
                // issue load x(t+4) into slot (u+2)&3 (fire & forget)
                {
                    int tl = t + 4; tl = tl > SEQ - 1 ? SEQ - 1 : tl;
                    f32x4 nv = *(const f32x4*)(x + (size_t)tl * BH + qoff);
                    if      (u == 0) s2 = nv;
                    else if (u == 1) s3 = nv;
                    else if (u == 2) s0 = nv;
                    else             s1 = nv;
                }
                sync_lds();
            }
        }
    }
}

extern "C" void kernel_launch(void* const* d_in, const int* in_sizes, int n_in,
                              void* d_out, int out_size, void* d_ws, size_t ws_size,
                              hipStream_t stream) {
    const float* x  = (const float*)d_in[0];
    const float* h  = (const float*)d_in[1];
    const float* Wx = (const float*)d_in[2];
    const float* bx = (const float*)d_in[3];
    const float* Wh = (const float*)d_in[4];
    const float* bh = (const float*)d_in[5];
    float* out = (float*)d_out;

    rnn_kernel<<<dim3(NB / RPB), dim3(512), 0, stream>>>(x, h, Wx, bx, Wh, bh, out);
}

// Round 9
// 330.489 us; speedup vs baseline: 1.6247x; 1.0369x over previous
//
#include <hip/hip_runtime.h>
#include <stdint.h>

#define SEQ 1024
#define NB  1024
#define HD  64
#define BH  (NB*HD)            // elements per timestep plane
#define RPB 16                 // batch rows per block (one consumer wave)

typedef _Float16 f16x8 __attribute__((ext_vector_type(8)));
typedef float    f32x4 __attribute__((ext_vector_type(4)));
typedef uint32_t u32x4 __attribute__((ext_vector_type(4)));

#define L2E2 2.8853900817779268f   // 2*log2(e), folded into weights/bias

__device__ __forceinline__ uint32_t pkrtz(float a, float b) {
    auto h = __builtin_amdgcn_cvt_pkrtz(a, b);   // a->lo, b->hi
    return __builtin_bit_cast(uint32_t, h);
}
// z = 2*log2e*x prescaled: tanh(x) = 1 - 2/(1+exp2(z)).
// Overflow-safe: z>>0 -> exp2=inf -> rcp=0 -> 1; z<<0 -> exp2=0 -> rcp(1)=1 -> -1.
__device__ __forceinline__ float tanh_ps(float z) {
    float e = __builtin_amdgcn_exp2f(z);
    float r = __builtin_amdgcn_rcpf(e + 1.0f);
    return __builtin_fmaf(-2.0f, r, 1.0f);
}
// Barrier draining ONLY lgkmcnt: global loads/stores stay in flight.
__device__ __forceinline__ void sync_lds() {
    asm volatile("s_waitcnt lgkmcnt(0)" ::: "memory");
    __builtin_amdgcn_s_barrier();
    asm volatile("" ::: "memory");
}

__global__ __launch_bounds__(128, 1) void rnn_kernel(
    const float* __restrict__ x,  const float* __restrict__ h0,
    const float* __restrict__ Wx, const float* __restrict__ bx,
    const float* __restrict__ Wh, const float* __restrict__ bh,
    float* __restrict__ out)
{
    // xp ring: [group 0..2][slot 0..3][tile m][lane] f32x4 C-frags. 48 KB.
    // Producer writes group (k+2)%3 during period k; consumer reads group k%3.
    __shared__ __align__(16) f32x4 xpl[3][4][4][64];

    const int tid  = threadIdx.x;
    const int w    = tid >> 6;         // 0 = consumer, 1 = producer
    const int lane = tid & 63;
    const int g    = lane >> 4;        // 16-lane group
    const int n    = lane & 15;        // MFMA col = batch row
    const int R0   = blockIdx.x * RPB;
    const size_t row = (size_t)(R0 + n) * HD;

    if (w == 0) {
        // ======== CONSUMER: self-contained recurrence, 16 rows x 64 ch ========
        // K-permuted prescaled Wh A-frags (R5-verified):
        // whA[m][T] elem e (k=8g+e) = Wh[16m+n][16(e>>1)+4g+2T+(e&1)] * L2E2
        f16x8 whA[4][2];
        #pragma unroll
        for (int m = 0; m < 4; ++m)
            #pragma unroll
            for (int T = 0; T < 2; ++T) {
                u32x4 dw;
                #pragma unroll
                for (int q = 0; q < 4; ++q) {
                    float2 wv = *(const float2*)(Wh + (size_t)(16*m + n) * HD + 16*q + 4*g + 2*T);
                    dw[q] = pkrtz(wv.x * L2E2, wv.y * L2E2);
                }
                whA[m][T] = __builtin_bit_cast(f16x8, dw);
            }
        // h(0) B-frags (permuted layout): fhT dword q = h0[row][16q+4g+2T..+1]
        f16x8 fh0, fh1;
        {
            u32x4 c0, c1;
            #pragma unroll
            for (int q = 0; q < 4; ++q) {
                f32x4 v = *(const f32x4*)(h0 + row + 16*q + 4*g);
                c0[q] = pkrtz(v[0], v[1]);
                c1[q] = pkrtz(v[2], v[3]);
            }
            fh0 = __builtin_bit_cast(f16x8, c0);
            fh1 = __builtin_bit_cast(f16x8, c1);
        }

        sync_lds();                     // prologue: xp groups 0,1 (steps 0..7) ready
        __builtin_amdgcn_s_setprio(1);

        f32x4 xpA[4], xpB[4];
        #pragma unroll
        for (int m = 0; m < 4; ++m) xpA[m] = xpl[0][0][m][lane];   // xp(0)

        // one recurrence step: consume cur=xp(t), prefetch nxt=xp(t+1) from [pg][ps]
        auto step = [&](int t, f32x4 (&cur)[4], f32x4 (&nxt)[4], int pg, int ps) {
            #pragma unroll
            for (int m = 0; m < 4; ++m) nxt[m] = xpl[pg][ps][m][lane];

            f32x4 acc[4];
            #pragma unroll
            for (int m = 0; m < 4; ++m)
                acc[m] = __builtin_amdgcn_mfma_f32_16x16x32_f16(whA[m][0], fh0, cur[m], 0, 0, 0);
            #pragma unroll
            for (int m = 0; m < 4; ++m)
                acc[m] = __builtin_amdgcn_mfma_f32_16x16x32_f16(whA[m][1], fh1, acc[m], 0, 0, 0);

            f32x4 tv[4];
            u32x4 c0, c1;
            #pragma unroll
            for (int m = 0; m < 4; ++m) {
                #pragma unroll
                for (int r = 0; r < 4; ++r) tv[m][r] = tanh_ps(acc[m][r]);
                c0[m] = pkrtz(tv[m][0], tv[m][1]);
                c1[m] = pkrtz(tv[m][2], tv[m][3]);
            }
            fh0 = __builtin_bit_cast(f16x8, c0);   // h(t+1) IS the next B-frag
            fh1 = __builtin_bit_cast(f16x8, c1);

            float* dst = out + (size_t)t * BH + row + 4*g;
            #pragma unroll
            for (int m = 0; m < 4; ++m) *(f32x4*)(dst + 16*m) = tv[m];
            if (t == SEQ - 1) {
                #pragma unroll
                for (int m = 0; m < 4; ++m) *(f32x4*)(dst + BH + 16*m) = tv[m];
            }
        };

        int cg = 0;
        for (int k = 0; k < SEQ/4; ++k) {
            const int ng = (cg == 2) ? 0 : cg + 1;
            step(4*k + 0, xpA, xpB, cg, 1);
            step(4*k + 1, xpB, xpA, cg, 2);
            step(4*k + 2, xpA, xpB, cg, 3);
            step(4*k + 3, xpB, xpA, ng, 0);   // next period's slot 0
            cg = ng;
            sync_lds();
        }
    } else {
        // ======== PRODUCER: xp(s) = Wx*x(s) + b into the LDS ring ========
        f16x8 wxA[4][2];
        f32x4 biasf[4];
        // x slice ring: sx[slot][q] <- x(s) plane slice; preload x(0..3)
        f32x4 sx[4][4];
        #pragma unroll
        for (int s = 0; s < 4; ++s) {
            const float* xs = x + (size_t)s * BH + row;
            #pragma unroll
            for (int q = 0; q < 4; ++q) sx[s][q] = *(const f32x4*)(xs + 16*q + 4*g);
        }
        #pragma unroll
        for (int m = 0; m < 4; ++m)
            #pragma unroll
            for (int T = 0; T < 2; ++T) {
                u32x4 dx;
                #pragma unroll
                for (int q = 0; q < 4; ++q) {
                    float2 xv = *(const float2*)(Wx + (size_t)(16*m + n) * HD + 16*q + 4*g + 2*T);
                    dx[q] = pkrtz(xv.x * L2E2, xv.y * L2E2);
                }
                wxA[m][T] = __builtin_bit_cast(f16x8, dx);
            }
        #pragma unroll
        for (int m = 0; m < 4; ++m) {
            f32x4 b1 = *(const f32x4*)(bh + 16*m + 4*g);
            f32x4 b2 = *(const f32x4*)(bx + 16*m + 4*g);
            biasf[m] = (b1 + b2) * L2E2;
        }

        // compute xp(s) from sx[slot], write to xpl[pg][ps], refill slot with x(s+4)
        auto produce = [&](int s, int slot, int pg, int ps) {
            u32x4 c0, c1;
            #pragma unroll
            for (int q = 0; q < 4; ++q) {
                f32x4 v = sx[slot][q];
                c0[q] = pkrtz(v[0], v[1]);
                c1[q] = pkrtz(v[2], v[3]);
            }
            f16x8 fx0 = __builtin_bit_cast(f16x8, c0);
            f16x8 fx1 = __builtin_bit_cast(f16x8, c1);
            #pragma unroll
            for (int m = 0; m < 4; ++m) {
                f32x4 tq = __builtin_amdgcn_mfma_f32_16x16x32_f16(wxA[m][0], fx0, biasf[m], 0, 0, 0);
                xpl[pg][ps][m][lane] =
                    __builtin_amdgcn_mfma_f32_16x16x32_f16(wxA[m][1], fx1, tq, 0, 0, 0);
            }
            int tl = s + 4; tl = tl > SEQ - 1 ? SEQ - 1 : tl;
            const float* xs = x + (size_t)tl * BH + row;
            #pragma unroll
            for (int q = 0; q < 4; ++q) sx[slot][q] = *(const f32x4*)(xs + 16*q + 4*g);
        };

        // prologue: fill groups 0,1 with xp(0..7)
        #pragma unroll
        for (int s = 0; s < 8; ++s) produce(s, s & 3, s >> 2, s & 3);
        sync_lds();

        int pg = 2;                         // period k writes group (k+2)%3
        for (int k = 0; k < SEQ/4; ++k) {
            if (k < SEQ/4 - 2) {
                const int s0 = 4*k + 8;
                produce(s0 + 0, 0, pg, 0);
                produce(s0 + 1, 1, pg, 1);
                produce(s0 + 2, 2, pg, 2);
                produce(s0 + 3, 3, pg, 3);
            }
            pg = (pg == 2) ? 0 : pg + 1;
            sync_lds();
        }
    }
}

extern "C" void kernel_launch(void* const* d_in, const int* in_sizes, int n_in,
                              void* d_out, int out_size, void* d_ws, size_t ws_size,
                              hipStream_t stream) {
    const float* x  = (const float*)d_in[0];
    const float* h  = (const float*)d_in[1];
    const float* Wx = (const float*)d_in[2];
    const float* bx = (const float*)d_in[3];
    const float* Wh = (const float*)d_in[4];
    const float* bh = (const float*)d_in[5];
    float* out = (float*)d_out;

    rnn_kernel<<<dim3(NB / RPB), dim3(128), 0, stream>>>(x, h, Wx, bx, Wh, bh, out);
}

// Round 10
// 314.449 us; speedup vs baseline: 1.7076x; 1.0510x over previous
//
#include <hip/hip_runtime.h>
#include <stdint.h>

#define SEQ 1024
#define NB  1024
#define HD  64
#define BH  (NB*HD)            // elements per timestep plane
#define RPB 16                 // batch rows per block (one consumer wave)

typedef _Float16 f16x8 __attribute__((ext_vector_type(8)));
typedef float    f32x4 __attribute__((ext_vector_type(4)));
typedef uint32_t u32x4 __attribute__((ext_vector_type(4)));

#define L2E2 2.8853900817779268f   // 2*log2(e), folded into weights/bias

__device__ __forceinline__ uint32_t pkrtz(float a, float b) {
    auto h = __builtin_amdgcn_cvt_pkrtz(a, b);   // a->lo, b->hi
    return __builtin_bit_cast(uint32_t, h);
}
// z = 2*log2e*x prescaled: tanh(x) = 1 - 2/(1+exp2(z)). Overflow-safe.
__device__ __forceinline__ float tanh_ps(float z) {
    float e = __builtin_amdgcn_exp2f(z);
    float r = __builtin_amdgcn_rcpf(e + 1.0f);
    return __builtin_fmaf(-2.0f, r, 1.0f);
}
// Barrier draining ONLY lgkmcnt: global loads/stores stay in flight.
__device__ __forceinline__ void sync_lds() {
    asm volatile("s_waitcnt lgkmcnt(0)" ::: "memory");
    __builtin_amdgcn_s_barrier();
    asm volatile("" ::: "memory");
}

__global__ __launch_bounds__(128, 1) void rnn_kernel(
    const float* __restrict__ x,  const float* __restrict__ h0,
    const float* __restrict__ Wx, const float* __restrict__ bx,
    const float* __restrict__ Wh, const float* __restrict__ bh,
    float* __restrict__ out)
{
    // xp ring: [group 0..2][slot 0..7][tile m][lane] f32x4 C-frags. 96 KB.
    // Period k (8 steps): consumer reads group k%3; producer writes (k+2)%3.
    __shared__ __align__(16) f32x4 xpl[3][8][4][64];

    const int tid  = threadIdx.x;
    const int w    = tid >> 6;         // 0 = consumer, 1 = producer
    const int lane = tid & 63;
    const int g    = lane >> 4;        // 16-lane group
    const int n    = lane & 15;        // MFMA col = batch row
    const int R0   = blockIdx.x * RPB;
    const size_t row = (size_t)(R0 + n) * HD;

    if (w == 0) {
        // ======== CONSUMER: self-contained recurrence, 16 rows x 64 ch ========
        // K-permuted prescaled Wh A-frags:
        // whA[m][T] elem e (k=8g+e) = Wh[16m+n][16(e>>1)+4g+2T+(e&1)] * L2E2
        f16x8 whA[4][2];
        #pragma unroll
        for (int m = 0; m < 4; ++m)
            #pragma unroll
            for (int T = 0; T < 2; ++T) {
                u32x4 dw;
                #pragma unroll
                for (int q = 0; q < 4; ++q) {
                    float2 wv = *(const float2*)(Wh + (size_t)(16*m + n) * HD + 16*q + 4*g + 2*T);
                    dw[q] = pkrtz(wv.x * L2E2, wv.y * L2E2);
                }
                whA[m][T] = __builtin_bit_cast(f16x8, dw);
            }
        // h(0) B-frags (permuted layout)
        f16x8 fh0, fh1;
        {
            u32x4 c0, c1;
            #pragma unroll
            for (int q = 0; q < 4; ++q) {
                f32x4 v = *(const f32x4*)(h0 + row + 16*q + 4*g);
                c0[q] = pkrtz(v[0], v[1]);
                c1[q] = pkrtz(v[2], v[3]);
            }
            fh0 = __builtin_bit_cast(f16x8, c0);
            fh1 = __builtin_bit_cast(f16x8, c1);
        }

        sync_lds();                     // barrier#0: groups 0,1 (xp 0..15) ready
        __builtin_amdgcn_s_setprio(1);

        f32x4 xq0[4], xq1[4];
        #pragma unroll
        for (int m = 0; m < 4; ++m) xq0[m] = xpl[0][0][m][lane];   // xp(0)

        float* optr = out + row + 4*g;

        // one step: consume cur, prefetch nxt from pre[slot] (slot static),
        // advance optr; LAST does the h_last duplicate store.
        auto stepj = [&](f32x4 (&cur)[4], f32x4 (&nxt)[4],
                         const f32x4 (*pre)[4][64], int slot, bool LAST) {
            #pragma unroll
            for (int m = 0; m < 4; ++m) nxt[m] = pre[slot][m][lane];

            f32x4 acc[4];
            #pragma unroll
            for (int m = 0; m < 4; ++m)
                acc[m] = __builtin_amdgcn_mfma_f32_16x16x32_f16(whA[m][0], fh0, cur[m], 0, 0, 0);
            #pragma unroll
            for (int m = 0; m < 4; ++m)
                acc[m] = __builtin_amdgcn_mfma_f32_16x16x32_f16(whA[m][1], fh1, acc[m], 0, 0, 0);

            f32x4 tv[4];
            u32x4 c0, c1;
            #pragma unroll
            for (int m = 0; m < 4; ++m) {
                #pragma unroll
                for (int r = 0; r < 4; ++r) tv[m][r] = tanh_ps(acc[m][r]);
                c0[m] = pkrtz(tv[m][0], tv[m][1]);
                c1[m] = pkrtz(tv[m][2], tv[m][3]);
            }
            fh0 = __builtin_bit_cast(f16x8, c0);   // h(t+1) IS the next B-frag
            fh1 = __builtin_bit_cast(f16x8, c1);

            #pragma unroll
            for (int m = 0; m < 4; ++m) *(f32x4*)(optr + 16*m) = tv[m];
            optr += BH;
            if (LAST) {     // h_last plane duplicate
                #pragma unroll
                for (int m = 0; m < 4; ++m) *(f32x4*)(optr + 16*m) = tv[m];
            }
        };

        int cg = 0, ng = 1;
        for (int k = 0; k < 128; ++k) {
            const f32x4 (*gc)[4][64] = &xpl[cg][0];
            const f32x4 (*gn)[4][64] = &xpl[ng][0];
            const bool lastk = (k == 127);
            #pragma unroll
            for (int j = 0; j < 8; ++j) {
                f32x4 (&cur)[4] = (j & 1) ? xq1 : xq0;
                f32x4 (&nxt)[4] = (j & 1) ? xq0 : xq1;
                if (j < 7) stepj(cur, nxt, gc, j + 1, false);
                else       stepj(cur, nxt, gn, 0,     lastk);
            }
            cg = ng; ng = (ng == 2) ? 0 : ng + 1;
            sync_lds();
        }
    } else {
        // ======== PRODUCER: xp(s) = Wx*x(s) + b into the LDS ring ========
        f16x8 wxA[4][2];
        f32x4 biasf[4];
        #pragma unroll
        for (int m = 0; m < 4; ++m)
            #pragma unroll
            for (int T = 0; T < 2; ++T) {
                u32x4 dx;
                #pragma unroll
                for (int q = 0; q < 4; ++q) {
                    float2 xv = *(const float2*)(Wx + (size_t)(16*m + n) * HD + 16*q + 4*g + 2*T);
                    dx[q] = pkrtz(xv.x * L2E2, xv.y * L2E2);
                }
                wxA[m][T] = __builtin_bit_cast(f16x8, dx);
            }
        #pragma unroll
        for (int m = 0; m < 4; ++m) {
            f32x4 b1 = *(const f32x4*)(bh + 16*m + 4*g);
            f32x4 b2 = *(const f32x4*)(bx + 16*m + 4*g);
            biasf[m] = (b1 + b2) * L2E2;
        }

        // pack 4 f32x4 slices -> B-frags, 2-chained MFMA, write xp C-frag
        auto mfma_xp = [&](const f32x4 (&v)[4], f32x4* dst) {
            u32x4 c0, c1;
            #pragma unroll
            for (int q = 0; q < 4; ++q) {
                c0[q] = pkrtz(v[q][0], v[q][1]);
                c1[q] = pkrtz(v[q][2], v[q][3]);
            }
            f16x8 fx0 = __builtin_bit_cast(f16x8, c0);
            f16x8 fx1 = __builtin_bit_cast(f16x8, c1);
            #pragma unroll
            for (int m = 0; m < 4; ++m) {
                f32x4 tq = __builtin_amdgcn_mfma_f32_16x16x32_f16(wxA[m][0], fx0, biasf[m], 0, 0, 0);
                dst[m * 64] = __builtin_amdgcn_mfma_f32_16x16x32_f16(wxA[m][1], fx1, tq, 0, 0, 0);
            }
        };

        // prologue: xp(0..15) -> groups 0,1
        for (int s = 0; s < 16; ++s) {
            f32x4 v[4];
            const float* xs = x + (size_t)s * BH + row;
            #pragma unroll
            for (int q = 0; q < 4; ++q) v[q] = *(const f32x4*)(xs + 16*q + 4*g);
            mfma_xp(v, &xpl[s >> 3][s & 7][0][lane]);
        }
        // reg ring: slot j&3 holds x(16+j); preload x(16..19)
        f32x4 ring[4][4];
        #pragma unroll
        for (int j = 0; j < 4; ++j) {
            const float* xs = x + (size_t)(16 + j) * BH + row;
            #pragma unroll
            for (int q = 0; q < 4; ++q) ring[j][q] = *(const f32x4*)(xs + 16*q + 4*g);
        }
        sync_lds();                       // barrier#0

        int pg = 2;
        for (int k = 0; k < 128; ++k) {
            if (k < 126) {
                f32x4 (*gp)[4][64] = &xpl[pg][0];
                const int sbase = 8 * k + 16;
                #pragma unroll
                for (int j = 0; j < 8; ++j) {
                    mfma_xp(ring[j & 3], &gp[j][0][lane]);   // xp(sbase+j)
                    int tl = sbase + j + 4; tl = tl > SEQ - 1 ? SEQ - 1 : tl;
                    const float* xs = x + (size_t)tl * BH + row;
                    #pragma unroll
                    for (int q = 0; q < 4; ++q) ring[j & 3][q] = *(const f32x4*)(xs + 16*q + 4*g);
                }
            }
            pg = (pg == 2) ? 0 : pg + 1;
            sync_lds();
        }
    }
}

extern "C" void kernel_launch(void* const* d_in, const int* in_sizes, int n_in,
                              void* d_out, int out_size, void* d_ws, size_t ws_size,
                              hipStream_t stream) {
    const float* x  = (const float*)d_in[0];
    const float* h  = (const float*)d_in[1];
    const float* Wx = (const float*)d_in[2];
    const float* bx = (const float*)d_in[3];
    const float* Wh = (const float*)d_in[4];
    const float* bh = (const float*)d_in[5];
    float* out = (float*)d_out;

    rnn_kernel<<<dim3(NB / RPB), dim3(128), 0, stream>>>(x, h, Wx, bx, Wh, bh, out);
}